// Round 1
// baseline (4228.834 us; speedup 1.0000x reference)
//
#include <hip/hip_runtime.h>

#define NPART 4096
#define E_TOT 262144
#define HID   128
#define FDOF  6
#define EPB   8                       // edges per block-iteration
#define NTILES (E_TOT / EPB)          // 32768

__global__ __launch_bounds__(128) void pairvel_fp32_kernel(
    const float* __restrict__ rel,       // [N,N,3]
    const int*   __restrict__ tgt,       // [E]
    const int*   __restrict__ src,       // [E]
    const float* __restrict__ force,     // [N,6]
    const float* __restrict__ visc,      // [1]
    const float* __restrict__ medianp,   // [1]
    const float* __restrict__ contactp,  // [1]
    const float* __restrict__ W1,        // [19,128]
    const float* __restrict__ b1,        // [128]
    const float* __restrict__ W2,        // [128,128]
    const float* __restrict__ b2,        // [128]
    const float* __restrict__ W3,        // [128,6]
    const float* __restrict__ b3,        // [6]
    float* __restrict__ out)             // [N,6]
{
    const int j    = threadIdx.x;   // hidden unit owned by this thread
    const int lane = j & 63;
    const int wid  = j >> 6;

    // ---- weights in registers: thread j holds column j of W1/W2, row j of W3
    float W1c[20], W2c[HID], W3r[FDOF];
    #pragma unroll
    for (int i = 0; i < 19; ++i) W1c[i] = W1[i * HID + j];
    W1c[19] = 0.f;
    #pragma unroll
    for (int k = 0; k < HID; ++k) W2c[k] = W2[k * HID + j];
    #pragma unroll
    for (int d = 0; d < FDOF; ++d) W3r[d] = W3[j * FDOF + d];
    const float b1j = b1[j], b2j = b2[j];
    const float inv_mu  = 1.0f / visc[0];
    const float median  = medianp[0];
    const float contact = contactp[0];

    __shared__ __align__(16) float x_lds[EPB][20];    // 19 feats + zero pad
    __shared__ __align__(16) float h1_lds[EPB][132];  // padded row
    __shared__ float vpart[EPB][FDOF][2];

    for (int tile = blockIdx.x; tile < NTILES; tile += gridDim.x) {
        const int e0 = tile * EPB;

        // ---- gather + feature build into LDS --------------------------------
        for (int t = j; t < EPB * 20; t += 128) {
            const int e = t / 20, i = t % 20;
            float val = 0.f;
            if (i < 19) {
                const int eg = e0 + e;
                const int tg = tgt[eg], sg = src[eg];
                if (i < 7) {
                    const float* rp = rel + ((size_t)tg * NPART + sg) * 3;
                    if (i < 3) {
                        val = rp[i];
                    } else {
                        const float x0 = rp[0], x1 = rp[1], x2 = rp[2];
                        const float dist =
                            fmaxf(sqrtf(x0*x0 + x1*x1 + x2*x2), 1e-8f);
                        if (i == 3) val = dist;
                        else if (i == 6) val = dist - contact;
                        else { float rs = dist - median; rs *= rs;
                               val = (i == 4) ? rs : rs * rs; }
                    }
                } else if (i < 13) {
                    val = force[tg * FDOF + (i - 7)];
                } else {
                    val = force[sg * FDOF + (i - 13)];
                }
            }
            x_lds[e][i] = val;
        }
        __syncthreads();

        // ---- layer 1: h1 = relu(x @ W1 + b1) --------------------------------
        #pragma unroll
        for (int e = 0; e < EPB; ++e) {
            float a = b1j;
            #pragma unroll
            for (int q = 0; q < 5; ++q) {
                const float4 xv =
                    *reinterpret_cast<const float4*>(&x_lds[e][q * 4]);
                a = fmaf(xv.x, W1c[q*4+0], a);
                a = fmaf(xv.y, W1c[q*4+1], a);
                a = fmaf(xv.z, W1c[q*4+2], a);
                a = fmaf(xv.w, W1c[q*4+3], a);
            }
            h1_lds[e][j] = fmaxf(a, 0.f);
        }
        __syncthreads();

        // ---- layer 2: h2 = relu(h1 @ W2 + b2), 8 independent chains ---------
        float acc[EPB];
        #pragma unroll
        for (int e = 0; e < EPB; ++e) acc[e] = b2j;
        #pragma unroll
        for (int kq = 0; kq < HID / 4; ++kq) {
            #pragma unroll
            for (int e = 0; e < EPB; ++e) {
                const float4 hv =
                    *reinterpret_cast<const float4*>(&h1_lds[e][kq * 4]);
                acc[e] = fmaf(hv.x, W2c[kq*4+0], acc[e]);
                acc[e] = fmaf(hv.y, W2c[kq*4+1], acc[e]);
                acc[e] = fmaf(hv.z, W2c[kq*4+2], acc[e]);
                acc[e] = fmaf(hv.w, W2c[kq*4+3], acc[e]);
            }
        }

        // ---- layer 3: vel = (h2 @ W3 + b3)/mu, butterfly reduce over j ------
        #pragma unroll
        for (int e = 0; e < EPB; ++e) {
            const float h2 = fmaxf(acc[e], 0.f);
            float pd[FDOF];
            #pragma unroll
            for (int d = 0; d < FDOF; ++d) pd[d] = h2 * W3r[d];
            #pragma unroll
            for (int m = 1; m < 64; m <<= 1) {
                #pragma unroll
                for (int d = 0; d < FDOF; ++d)
                    pd[d] += __shfl_xor(pd[d], m);
            }
            if (lane == 0) {
                #pragma unroll
                for (int d = 0; d < FDOF; ++d) vpart[e][d][wid] = pd[d];
            }
        }
        __syncthreads();

        // ---- combine 2 waves, scale, scatter-add ----------------------------
        if (j < EPB * FDOF) {
            const int e = j / FDOF, d = j % FDOF;
            const float v =
                (vpart[e][d][0] + vpart[e][d][1] + b3[d]) * inv_mu;
            atomicAdd(&out[(size_t)tgt[e0 + e] * FDOF + d], v);
        }
        __syncthreads();
    }
}

extern "C" void kernel_launch(void* const* d_in, const int* in_sizes, int n_in,
                              void* d_out, int out_size, void* d_ws, size_t ws_size,
                              hipStream_t stream) {
    const float* rel   = (const float*)d_in[0];
    const int*   tgt   = (const int*)d_in[1];
    const int*   src   = (const int*)d_in[2];
    const float* force = (const float*)d_in[3];
    const float* visc  = (const float*)d_in[4];
    const float* med   = (const float*)d_in[5];
    const float* con   = (const float*)d_in[6];
    const float* W1    = (const float*)d_in[7];
    const float* b1    = (const float*)d_in[8];
    const float* W2    = (const float*)d_in[9];
    const float* b2    = (const float*)d_in[10];
    const float* W3    = (const float*)d_in[11];
    const float* b3    = (const float*)d_in[12];
    float* out = (float*)d_out;

    hipMemsetAsync(out, 0, (size_t)out_size * sizeof(float), stream);
    pairvel_fp32_kernel<<<1024, 128, 0, stream>>>(
        rel, tgt, src, force, visc, med, con, W1, b1, W2, b2, W3, b3, out);
}